// Round 7
// baseline (789.456 us; speedup 1.0000x reference)
//
#include <hip/hip_runtime.h>
#include <math.h>
#include <stdint.h>

#define DD 1024
#define EE 8
#define FF 4096
#define CAPV 2048
#define TT 8192
#define LIST_STRIDE 4096   // per-expert entry capacity (2*CAP)

typedef __bf16 bf16x8 __attribute__((ext_vector_type(8)));
typedef __bf16 bf16x4 __attribute__((ext_vector_type(4)));
typedef float floatx4 __attribute__((ext_vector_type(4)));

typedef __attribute__((address_space(3))) unsigned int as3_uint;
typedef __attribute__((address_space(1))) const unsigned int as1_uint;

__device__ __forceinline__ void gl_lds16(const void* g, void* l) {
    __builtin_amdgcn_global_load_lds((as1_uint*)g, (as3_uint*)l, 16, 0, 0);
}

__device__ __forceinline__ unsigned short f2bf(float f) {
    union { float f; unsigned int u; } v; v.f = f;
    const unsigned int r = v.u + 0x7FFFu + ((v.u >> 16) & 1u);
    return (unsigned short)(r >> 16);
}

// ---------------- fused prep: gate (blocks 0..255) + w1/w2 transpose --------
// sums layout: [0]=pa [1]=z [2..9]=P [10..17]=p6 [18..25]=n1 counts (as float)
#define GATE_BLOCKS 256
#define T1_BLOCKS 16384   // (DD/64=16) x (FF/32=128) x 8
#define T2_BLOCKS 16384   // (FF/64=64) x (DD/32=32) x 8

__device__ __forceinline__ void transpose_body(
    const float* __restrict__ in, __bf16* __restrict__ out,
    int K, int N, int bk, int bn, int e, float (*tile)[65], int tid)
{
    const float* ine = in + (size_t)e * K * N;
    __bf16* oute = out + (size_t)e * K * N;
    #pragma unroll
    for (int p = 0; p < 8; ++p) {
        const int idx = p * 256 + tid;       // 0..2047
        const int kl = idx >> 5, nl = idx & 31;
        tile[nl][kl] = ine[(size_t)(bk + kl) * N + bn + nl];
    }
    __syncthreads();
    #pragma unroll
    for (int p = 0; p < 4; ++p) {
        const int wdx = p * 256 + tid;       // 0..1023
        const int nl = wdx >> 5, c = wdx & 31;
        const unsigned int pk = (unsigned int)f2bf(tile[nl][c * 2])
                              | ((unsigned int)f2bf(tile[nl][c * 2 + 1]) << 16);
        *(unsigned int*)&oute[(size_t)(bn + nl) * K + bk + c * 2] = pk;
    }
}

__global__ __launch_bounds__(256) void moe_prep_kernel(
    const float* __restrict__ x, const float* __restrict__ gw,
    int* __restrict__ e1o, int* __restrict__ e2o,
    float* __restrict__ g1o, float* __restrict__ g2o,
    float* __restrict__ sums, __bf16* __restrict__ xb,
    const float* __restrict__ w1, __bf16* __restrict__ w1T,
    const float* __restrict__ w2, __bf16* __restrict__ w2T)
{
    __shared__ float smem[EE * DD];        // 32 KB (gate gw / transpose tile)
    __shared__ float wp[4][26];
    const int bid = blockIdx.x;
    const int tid = threadIdx.x;

    if (bid >= GATE_BLOCKS) {
        float (*tile)[65] = (float (*)[65])smem;
        if (bid < GATE_BLOCKS + T1_BLOCKS) {
            const int f = bid - GATE_BLOCKS;
            transpose_body(w1, w1T, DD, FF, (f & 15) * 64, ((f >> 4) & 127) * 32,
                           f >> 11, tile, tid);
        } else {
            const int f = bid - GATE_BLOCKS - T1_BLOCKS;
            transpose_body(w2, w2T, FF, DD, (f & 63) * 64, ((f >> 6) & 31) * 32,
                           f >> 11, tile, tid);
        }
        return;
    }

    float (*sgw)[DD] = (float (*)[DD])smem;
    for (int i = tid; i < EE * DD; i += 256) sgw[i >> 10][i & 1023] = gw[i];
    __syncthreads();

    const int wave = tid >> 6, lane = tid & 63;
    const int gwave = bid * 4 + wave;
    const int nwaves = GATE_BLOCKS * 4;

    float pa_acc = 0.f, z_acc = 0.f;
    float P_acc[EE] = {0}, p6_acc[EE] = {0};
    int n1_acc[EE] = {0};

    for (int t = gwave; t < TT; t += nwaves) {
        float acc[EE] = {0};
        const float* xr = x + (size_t)t * DD;
        __bf16* xbr = xb + (size_t)t * DD;
        #pragma unroll
        for (int i = 0; i < DD / 64; ++i) {
            const float xv = xr[lane + 64 * i];
            xbr[lane + 64 * i] = (__bf16)xv;
            #pragma unroll
            for (int e = 0; e < EE; ++e) acc[e] += xv * sgw[e][lane + 64 * i];
        }
        #pragma unroll
        for (int e = 0; e < EE; ++e) {
            float v = acc[e];
            #pragma unroll
            for (int off = 32; off > 0; off >>= 1) v += __shfl_xor(v, off, 64);
            acc[e] = v;
        }
        if (lane == 0) {
            float mx = acc[0];
            #pragma unroll
            for (int e = 1; e < EE; ++e) mx = fmaxf(mx, acc[e]);
            float pr[EE], p6[EE], se = 0.f, s6 = 0.f;
            #pragma unroll
            for (int e = 0; e < EE; ++e) {
                pr[e] = __expf(acc[e] - mx); se += pr[e];
                p6[e] = __expf((acc[e] - mx) * (1.0f / 1.66f)); s6 += p6[e];
            }
            const float lse = mx + __logf(se);
            z_acc += lse * lse;
            const float ise = 1.f / se, is6 = 1.f / s6;
            #pragma unroll
            for (int e = 0; e < EE; ++e) {
                pr[e] *= ise; p6[e] *= is6;
                P_acc[e] += pr[e]; p6_acc[e] += p6[e];
                pa_acc += p6[e] * (1.f - p6[e]);
            }
            int a = 0;
            #pragma unroll
            for (int e = 1; e < EE; ++e) if (pr[e] > pr[a]) a = e;
            int b = (a == 0) ? 1 : 0;
            #pragma unroll
            for (int e = 0; e < EE; ++e) if (e != a && pr[e] > pr[b]) b = e;
            n1_acc[a]++;
            const float ga = pr[a], gb = pr[b], idn = 1.f / (ga + gb);
            e1o[t] = a; e2o[t] = b;
            g1o[t] = ga * idn; g2o[t] = gb * idn;
        }
    }
    if (lane == 0) {
        wp[wave][0] = pa_acc; wp[wave][1] = z_acc;
        #pragma unroll
        for (int e = 0; e < EE; ++e) {
            wp[wave][2 + e] = P_acc[e]; wp[wave][10 + e] = p6_acc[e];
            wp[wave][18 + e] = (float)n1_acc[e];
        }
    }
    __syncthreads();
    if (tid < 26) {
        const float s = wp[0][tid] + wp[1][tid] + wp[2][tid] + wp[3][tid];
        atomicAdd(&sums[tid], s);
    }
}

// ---------------- parallel ordered capacity scan: 16 blocks (slot, expert) --
__global__ __launch_bounds__(256) void moe_scan_kernel(
    const int* __restrict__ e1i, const int* __restrict__ e2i,
    const float* __restrict__ g1i, const float* __restrict__ g2i,
    const float* __restrict__ rnd, const float* __restrict__ sums,
    int* __restrict__ etok, int* __restrict__ p1o, int* __restrict__ p2o,
    int* __restrict__ cnt1, int* __restrict__ cnt2,
    float* __restrict__ imp1, float* __restrict__ imp2)
{
    const int bid = blockIdx.x, slot = bid >> 3, e = bid & 7;
    const int tid = threadIdx.x, wave = tid >> 6, lane = tid & 63;
    __shared__ int wtA[4], wtB[4];
    __shared__ float red[256];
    const int* ev = slot ? e2i : e1i;
    const float* gv = slot ? g2i : g1i;
    int* po = slot ? p2o : p1o;
    const int base = slot ? min((int)sums[18 + e], CAPV) : 0;

    int runTot = 0, runM = 0;
    float limp = 0.f;
    for (int c = 0; c < TT / 256; ++c) {
        const int t = c * 256 + tid;
        const int sel = (ev[t] == e) ? 1 : 0;
        const float w = gv[t];
        int ps = sel;
        #pragma unroll
        for (int off = 1; off < 64; off <<= 1) { int v = __shfl_up(ps, off, 64); if (lane >= off) ps += v; }
        if (lane == 63) wtA[wave] = ps;
        __syncthreads();
        int wpre = 0, ctot = 0;
        #pragma unroll
        for (int ww = 0; ww < 4; ++ww) { if (ww < wave) wpre += wtA[ww]; ctot += wtA[ww]; }
        const int pos = runTot + wpre + ps - 1;      // valid when sel
        int m, idx;
        if (slot == 0) {
            m = sel && (pos < CAPV);
            idx = pos;
        } else {
            m = (sel && (pos < CAPV) && (rnd[t] < 2.f * w)) ? 1 : 0;
            int pm = m;
            #pragma unroll
            for (int off = 1; off < 64; off <<= 1) { int v = __shfl_up(pm, off, 64); if (lane >= off) pm += v; }
            if (lane == 63) wtB[wave] = pm;
            __syncthreads();
            int wpm = 0, mtot = 0;
            #pragma unroll
            for (int ww = 0; ww < 4; ++ww) { if (ww < wave) wpm += wtB[ww]; mtot += wtB[ww]; }
            idx = runM + wpm + pm - 1;
            runM += mtot;
        }
        if (sel) po[t] = m ? (e * LIST_STRIDE + base + idx) : -1;
        if (m) {
            etok[e * LIST_STRIDE + base + idx] = t;
            limp += w;
        }
        runTot += ctot;
        __syncthreads();
    }
    red[tid] = limp; __syncthreads();
    for (int s = 128; s > 0; s >>= 1) { if (tid < s) red[tid] += red[tid + s]; __syncthreads(); }
    if (tid == 0) {
        if (slot == 0) { cnt1[e] = min(runTot, CAPV); imp1[e] = red[0]; }
        else           { cnt2[e] = runM;              imp2[e] = red[0]; }
    }
}

// ---------------- aux scalar ------------------------------------------------
__global__ void moe_aux_kernel(const float* __restrict__ sums,
                               const float* __restrict__ imp1, const float* __restrict__ imp2,
                               float* __restrict__ out_aux)
{
    if (threadIdx.x != 0 || blockIdx.x != 0) return;
    const float invT = 1.f / (float)TT;
    const float pa = sums[0] / ((float)TT * (float)EE);
    float pb = 0.f, load = 0.f, msum = 0.f;
    float im[EE];
    for (int e = 0; e < EE; ++e) {
        const float pm = sums[10 + e] * invT;
        pb += pm * (1.f - pm);
        load += (sums[18 + e] * invT) * (sums[2 + e] * invT);
        im[e] = imp1[e] + imp2[e];
        msum += im[e];
    }
    pb = 1.f / (float)EE - pb / (float)EE;
    const float penalty = 0.01f * (pa + pb);
    const float z_loss = 0.001f * sums[1] * invT;
    const float load_loss = 0.01f * (float)EE * load;
    const float mean = msum / (float)EE;
    float var = 0.f;
    for (int e = 0; e < EE; ++e) { const float d = im[e] - mean; var += d * d; }
    var /= (float)EE;
    const float imp_loss = 0.01f * var / (mean * mean);
    *out_aux = penalty + z_loss + load_loss + imp_loss;
}

// ============ FFN K-loop: verified 2-phase order, 2 blocks/CU ===============
// 128x128 tile, BK=64, 4 waves (2Mx2N), wave-tile 64x64, 64 KiB LDS dbuf.
// Per K-tile: STAGE(next) FIRST -> 16 ds_read_b128 -> lgkmcnt(0) ->
// setprio(1) 32 MFMA setprio(0) -> vmcnt(0) -> ONE s_barrier.
// Stage loads get the whole read+MFMA window before the drain; the second
// co-resident block on the CU covers the drain itself (m97/m114 mechanism).
// WAR: buf^1 (tile t-1) reads retired at iter t-1's lgkmcnt(0)+barrier.
// LDS swizzle: row r, logical k-chunk lc stored at phys chunk lc^(r&7) via
// pre-swizzled global source; reads XOR the same key (0 bank conflicts, R1).
#define FFN_CORE128(NT)                                                        \
    stage(0, 0);                                                               \
    asm volatile("s_waitcnt vmcnt(0)" ::: "memory");                           \
    __builtin_amdgcn_s_barrier();                                              \
    _Pragma("unroll 2")                                                        \
    for (int t = 0; t < (NT); ++t) {                                           \
        const int cur = t & 1;                                                 \
        if (t + 1 < (NT)) stage(cur ^ 1, (t + 1) * 64);                        \
        bf16x8 a0[4], a1[4], b0[4], b1[4];                                     \
        _Pragma("unroll")                                                      \
        for (int i = 0; i < 4; ++i) {                                          \
            a0[i] = *(const bf16x8*)&As[cur][ar[i] + sw0];                     \
            a1[i] = *(const bf16x8*)&As[cur][ar[i] + sw1];                     \
        }                                                                      \
        _Pragma("unroll")                                                      \
        for (int j = 0; j < 4; ++j) {                                          \
            b0[j] = *(const bf16x8*)&Bs[cur][br[j] + sw0];                     \
            b1[j] = *(const bf16x8*)&Bs[cur][br[j] + sw1];                     \
        }                                                                      \
        asm volatile("s_waitcnt lgkmcnt(0)" ::: "memory");                     \
        __builtin_amdgcn_s_setprio(1);                                         \
        _Pragma("unroll")                                                      \
        for (int i = 0; i < 4; ++i)                                            \
            _Pragma("unroll")                                                  \
            for (int j = 0; j < 4; ++j)                                        \
                acc[i][j] = __builtin_amdgcn_mfma_f32_16x16x32_bf16(           \
                    b0[j], a0[i], acc[i][j], 0, 0, 0);                         \
        _Pragma("unroll")                                                      \
        for (int i = 0; i < 4; ++i)                                            \
            _Pragma("unroll")                                                  \
            for (int j = 0; j < 4; ++j)                                        \
                acc[i][j] = __builtin_amdgcn_mfma_f32_16x16x32_bf16(           \
                    b1[j], a1[i], acc[i][j], 0, 0, 0);                         \
        __builtin_amdgcn_s_setprio(0);                                         \
        asm volatile("s_waitcnt vmcnt(0)" ::: "memory");                       \
        __builtin_amdgcn_s_barrier();                                          \
    }

// ---------------- FFN pass 1: H = gelu(Xg @ W1 + b1) ------------------------
__global__ __launch_bounds__(256, 2) void moe_ffn1_mfma(
    const __bf16* __restrict__ xb, const __bf16* __restrict__ w1T,
    const float* __restrict__ b1, const int* __restrict__ etok,
    const int* __restrict__ cnt1, const int* __restrict__ cnt2,
    __bf16* __restrict__ H)
{
    const int f = blockIdx.x;                        // 8192 blocks
    const int xcd = f & 7, s = f >> 3;               // s in [0,1024)
    const int g = xcd * 32 + (s >> 5);               // 256 groups = (e, n-tile)
    const int e = g >> 5, n0 = (g & 31) * 128;
    const int m0 = (s & 31) * 128;
    const int ce = cnt1[e] + cnt2[e];
    if (m0 >= ce) return;
    const int tid = threadIdx.x, lane = tid & 63, w = tid >> 6;
    const int wm = w >> 1, wn = w & 1;
    const int quad = lane >> 4, l16 = lane & 15;

    __shared__ __bf16 As[2][8192];   // 128 rows x 64 k, chunk-XOR swizzled
    __shared__ __bf16 Bs[2][8192];   // 64 KiB total -> 2 blocks/CU

    // staging: 4 rounds/matrix; round q slot = q*256+tid -> row q*32+(tid>>3),
    // phys chunk tid&7; source pre-swizzled so logical chunk = pc ^ (row&7).
    const int srow = tid >> 3, spc = tid & 7;
    const __bf16* ap[4];
    const __bf16* bp[4];
    const __bf16* bbase = w1T + (size_t)e * FF * DD;
    #pragma unroll
    for (int q = 0; q < 4; ++q) {
        const int r = q * 32 + srow;
        const int gr = m0 + r;
        const int tok = (gr < ce) ? etok[e * LIST_STRIDE + gr] : 0;
        const int co = (spc ^ (r & 7)) * 8;
        ap[q] = xb + (size_t)tok * DD + co;
        bp[q] = bbase + (size_t)(n0 + r) * DD + co;
    }

    floatx4 acc[4][4];
    #pragma unroll
    for (int i = 0; i < 4; ++i)
        #pragma unroll
        for (int j = 0; j < 4; ++j) acc[i][j] = floatx4{0.f, 0.f, 0.f, 0.f};

    const int sw0 = (quad ^ (l16 & 7)) * 8;
    const int sw1 = ((4 + quad) ^ (l16 & 7)) * 8;
    int ar[4], br[4];
    #pragma unroll
    for (int i = 0; i < 4; ++i) ar[i] = (wm * 64 + i * 16 + l16) * 64;
    #pragma unroll
    for (int j = 0; j < 4; ++j) br[j] = (wn * 64 + j * 16 + l16) * 64;

    auto stage = [&](int bufi, int koff) {
        #pragma unroll
        for (int q = 0; q < 4; ++q)
            gl_lds16(ap[q] + koff, &As[bufi][q * 2048 + tid * 8]);
        #pragma unroll
        for (int q = 0; q < 4; ++q)
            gl_lds16(bp[q] + koff, &Bs[bufi][q * 2048 + tid * 8]);
    };

    FFN_CORE128(16)   // K = 1024

    // epilogue: bias + gelu, 8B stores (verified 16x16 C^T mapping)
    const float* b1e = b1 + (size_t)e * FF;
    #pragma unroll
    for (int i = 0; i < 4; ++i) {
        const int mrow = m0 + wm * 64 + i * 16 + l16;
        __bf16* hrow = H + ((size_t)e * LIST_STRIDE + mrow) * FF;
        #pragma unroll
        for (int j = 0; j < 4; ++j) {
            const int col0 = n0 + wn * 64 + j * 16 + quad * 4;
            const float4 bb = *(const float4*)&b1e[col0];
            float vv[4] = {acc[i][j][0] + bb.x, acc[i][j][1] + bb.y,
                           acc[i][j][2] + bb.z, acc[i][j][3] + bb.w};
            bf16x4 pk;
            #pragma unroll
            for (int r = 0; r < 4; ++r) {
                const float v = vv[r];
                const float u = 0.7978845608028654f * (v + 0.044715f * v * v * v);
                const float th = 1.f - 2.f / (__expf(2.f * u) + 1.f);
                pk[r] = (__bf16)(0.5f * v * (1.f + th));
            }
            *(bf16x4*)&hrow[col0] = pk;
        }
    }
}

// ---------------- FFN pass 2: O = H @ W2 + b2 -------------------------------
__global__ __launch_bounds__(256, 2) void moe_ffn2_mfma(
    const __bf16* __restrict__ H, const __bf16* __restrict__ w2T,
    const float* __restrict__ b2, const int* __restrict__ cnt1,
    const int* __restrict__ cnt2, __bf16* __restrict__ O)
{
    const int f = blockIdx.x;                        // 2048 blocks
    const int xcd = f & 7, s = f >> 3;               // s in [0,256)
    const int g = xcd * 8 + (s >> 5);                // 64 groups = (e, n-tile)
    const int e = g >> 3, n0 = (g & 7) * 128;
    const int m0 = (s & 31) * 128;
    const int ce = cnt1[e] + cnt2[e];
    if (m0 >= ce) return;
    const int tid = threadIdx.x, lane = tid & 63, w = tid >> 6;
    const int wm = w >> 1, wn = w & 1;
    const int quad = lane >> 4, l16 = lane & 15;

    __shared__ __bf16 As[2][8192];
    __shared__ __bf16 Bs[2][8192];

    const int srow = tid >> 3, spc = tid & 7;
    const __bf16* ap[4];
    const __bf16* bp[4];
    const __bf16* bbase = w2T + (size_t)e * DD * FF;
    #pragma unroll
    for (int q = 0; q < 4; ++q) {
        const int r = q * 32 + srow;
        const int co = (spc ^ (r & 7)) * 8;
        ap[q] = H + ((size_t)e * LIST_STRIDE + m0 + r) * FF + co;
        bp[q] = bbase + (size_t)(n0 + r) * FF + co;
    }

    floatx4 acc[4][4];
    #pragma unroll
    for (int i = 0; i < 4; ++i)
        #pragma unroll
        for (int j = 0; j < 4; ++j) acc[i][j] = floatx4{0.f, 0.f, 0.f, 0.f};

    const int sw0 = (quad ^ (l16 & 7)) * 8;
    const int sw1 = ((4 + quad) ^ (l16 & 7)) * 8;
    int ar[4], br[4];
    #pragma unroll
    for (int i = 0; i < 4; ++i) ar[i] = (wm * 64 + i * 16 + l16) * 64;
    #pragma unroll
    for (int j = 0; j < 4; ++j) br[j] = (wn * 64 + j * 16 + l16) * 64;

    auto stage = [&](int bufi, int koff) {
        #pragma unroll
        for (int q = 0; q < 4; ++q)
            gl_lds16(ap[q] + koff, &As[bufi][q * 2048 + tid * 8]);
        #pragma unroll
        for (int q = 0; q < 4; ++q)
            gl_lds16(bp[q] + koff, &Bs[bufi][q * 2048 + tid * 8]);
    };

    FFN_CORE128(64)   // K = 4096

    const float* b2e = b2 + (size_t)e * DD;
    #pragma unroll
    for (int i = 0; i < 4; ++i) {
        const int grow = m0 + wm * 64 + i * 16 + l16;
        if (grow < ce) {
            __bf16* orow = O + ((size_t)e * LIST_STRIDE + grow) * DD;
            #pragma unroll
            for (int j = 0; j < 4; ++j) {
                const int col0 = n0 + wn * 64 + j * 16 + quad * 4;
                const float4 bb = *(const float4*)&b2e[col0];
                bf16x4 pk;
                pk[0] = (__bf16)(acc[i][j][0] + bb.x);
                pk[1] = (__bf16)(acc[i][j][1] + bb.y);
                pk[2] = (__bf16)(acc[i][j][2] + bb.z);
                pk[3] = (__bf16)(acc[i][j][3] + bb.w);
                *(bf16x4*)&orow[col0] = pk;
            }
        }
    }
}

// ---------------- combine: y[t] = g1*O[p1[t]] + g2*O[p2[t]] -----------------
__global__ __launch_bounds__(256) void moe_combine_kernel(
    const __bf16* __restrict__ O, const float* __restrict__ g1v,
    const float* __restrict__ g2v, const int* __restrict__ p1v,
    const int* __restrict__ p2v, float* __restrict__ y)
{
    const int t = blockIdx.x;
    const int col = threadIdx.x * 4;
    const int p1 = p1v[t], p2 = p2v[t];
    float4 r = make_float4(0.f, 0.f, 0.f, 0.f);
    if (p1 >= 0) {
        const float g = g1v[t];
        const bf16x4 v = *(const bf16x4*)&O[(size_t)p1 * DD + col];
        r.x += g * (float)v[0]; r.y += g * (float)v[1];
        r.z += g * (float)v[2]; r.w += g * (float)v[3];
    }
    if (p2 >= 0) {
        const float g = g2v[t];
        const bf16x4 v = *(const bf16x4*)&O[(size_t)p2 * DD + col];
        r.x += g * (float)v[0]; r.y += g * (float)v[1];
        r.z += g * (float)v[2]; r.w += g * (float)v[3];
    }
    *(float4*)&y[(size_t)t * DD + col] = r;
}

// ---------------- launch ----------------------------------------------------
extern "C" void kernel_launch(void* const* d_in, const int* in_sizes, int n_in,
                              void* d_out, int out_size, void* d_ws, size_t ws_size,
                              hipStream_t stream) {
    const float* x   = (const float*)d_in[0];
    const float* gw  = (const float*)d_in[1];
    const float* w1  = (const float*)d_in[2];
    const float* b1  = (const float*)d_in[3];
    const float* w2  = (const float*)d_in[4];
    const float* b2  = (const float*)d_in[5];
    const float* rnd = (const float*)d_in[6];
    float* out = (float*)d_out;

    char* p = (char*)d_ws;
    float* sums = (float*)p;                 // 26 floats
    float* imp1 = (float*)(p + 128);         // 8 floats
    float* imp2 = (float*)(p + 160);         // 8 floats
    int*   cnt1 = (int*)(p + 192);           // 8 ints
    int*   cnt2 = (int*)(p + 224);           // 8 ints
    p += 512;
    int*   e1v = (int*)p;   p += TT * 4;
    int*   e2v = (int*)p;   p += TT * 4;
    float* g1v = (float*)p; p += TT * 4;
    float* g2v = (float*)p; p += TT * 4;
    int*   p1v = (int*)p;   p += TT * 4;
    int*   p2v = (int*)p;   p += TT * 4;
    int*   etok = (int*)p;  p += EE * LIST_STRIDE * 4;
    uintptr_t q = (((uintptr_t)p) + 255) & ~(uintptr_t)255;
    __bf16* xb  = (__bf16*)q;  q += (size_t)TT * DD * 2;             // 16 MB
    __bf16* w1T = (__bf16*)q;  q += (size_t)EE * FF * DD * 2;        // 64 MB
    __bf16* w2T = (__bf16*)q;  q += (size_t)EE * DD * FF * 2;        // 64 MB
    __bf16* H   = (__bf16*)q;  q += (size_t)EE * LIST_STRIDE * FF * 2; // 256 MB
    __bf16* O   = (__bf16*)q;                                        // 64 MB

    hipMemsetAsync(sums, 0, 128, stream);

    moe_prep_kernel<<<GATE_BLOCKS + T1_BLOCKS + T2_BLOCKS, 256, 0, stream>>>(
        x, gw, e1v, e2v, g1v, g2v, sums, xb, w1, w1T, w2, w2T);
    moe_scan_kernel<<<16, 256, 0, stream>>>(e1v, e2v, g1v, g2v, rnd, sums,
                                            etok, p1v, p2v, cnt1, cnt2, imp1, imp2);
    moe_aux_kernel<<<1, 64, 0, stream>>>(sums, imp1, imp2, out + (size_t)TT * DD);

    moe_ffn1_mfma<<<8192, 256, 0, stream>>>(xb, w1T, b1, etok, cnt1, cnt2, H);
    moe_ffn2_mfma<<<2048, 256, 0, stream>>>(H, w2T, b2, cnt1, cnt2, O);
    moe_combine_kernel<<<TT, 256, 0, stream>>>(O, g1v, g2v, p1v, p2v, out);
}

// Round 8
// 708.217 us; speedup vs baseline: 1.1147x; 1.1147x over previous
//
#include <hip/hip_runtime.h>
#include <math.h>
#include <stdint.h>

#define DD 1024
#define EE 8
#define FF 4096
#define CAPV 2048
#define TT 8192
#define LIST_STRIDE 4096   // per-expert entry capacity (2*CAP)

typedef __bf16 bf16x8 __attribute__((ext_vector_type(8)));
typedef __bf16 bf16x4 __attribute__((ext_vector_type(4)));
typedef float floatx4 __attribute__((ext_vector_type(4)));

typedef __attribute__((address_space(3))) unsigned int as3_uint;
typedef __attribute__((address_space(1))) const unsigned int as1_uint;

__device__ __forceinline__ void gl_lds16(const void* g, void* l) {
    __builtin_amdgcn_global_load_lds((as1_uint*)g, (as3_uint*)l, 16, 0, 0);
}

__device__ __forceinline__ unsigned short f2bf(float f) {
    union { float f; unsigned int u; } v; v.f = f;
    const unsigned int r = v.u + 0x7FFFu + ((v.u >> 16) & 1u);
    return (unsigned short)(r >> 16);
}

// ---------------- fused prep: gate (blocks 0..255) + w1/w2 transpose --------
// sums layout: [0]=pa [1]=z [2..9]=P [10..17]=p6 [18..25]=n1 counts (as float)
#define GATE_BLOCKS 256
#define T1_BLOCKS 16384   // (DD/64=16) x (FF/32=128) x 8
#define T2_BLOCKS 16384   // (FF/64=64) x (DD/32=32) x 8

__device__ __forceinline__ void transpose_body(
    const float* __restrict__ in, __bf16* __restrict__ out,
    int K, int N, int bk, int bn, int e, float (*tile)[65], int tid)
{
    const float* ine = in + (size_t)e * K * N;
    __bf16* oute = out + (size_t)e * K * N;
    #pragma unroll
    for (int p = 0; p < 8; ++p) {
        const int idx = p * 256 + tid;       // 0..2047
        const int kl = idx >> 5, nl = idx & 31;
        tile[nl][kl] = ine[(size_t)(bk + kl) * N + bn + nl];
    }
    __syncthreads();
    #pragma unroll
    for (int p = 0; p < 4; ++p) {
        const int wdx = p * 256 + tid;       // 0..1023
        const int nl = wdx >> 5, c = wdx & 31;
        const unsigned int pk = (unsigned int)f2bf(tile[nl][c * 2])
                              | ((unsigned int)f2bf(tile[nl][c * 2 + 1]) << 16);
        *(unsigned int*)&oute[(size_t)(bn + nl) * K + bk + c * 2] = pk;
    }
}

__global__ __launch_bounds__(256) void moe_prep_kernel(
    const float* __restrict__ x, const float* __restrict__ gw,
    int* __restrict__ e1o, int* __restrict__ e2o,
    float* __restrict__ g1o, float* __restrict__ g2o,
    float* __restrict__ sums, __bf16* __restrict__ xb,
    const float* __restrict__ w1, __bf16* __restrict__ w1T,
    const float* __restrict__ w2, __bf16* __restrict__ w2T)
{
    __shared__ float smem[EE * DD];        // 32 KB (gate gw / transpose tile)
    __shared__ float wp[4][26];
    const int bid = blockIdx.x;
    const int tid = threadIdx.x;

    if (bid >= GATE_BLOCKS) {
        float (*tile)[65] = (float (*)[65])smem;
        if (bid < GATE_BLOCKS + T1_BLOCKS) {
            const int f = bid - GATE_BLOCKS;
            transpose_body(w1, w1T, DD, FF, (f & 15) * 64, ((f >> 4) & 127) * 32,
                           f >> 11, tile, tid);
        } else {
            const int f = bid - GATE_BLOCKS - T1_BLOCKS;
            transpose_body(w2, w2T, FF, DD, (f & 63) * 64, ((f >> 6) & 31) * 32,
                           f >> 11, tile, tid);
        }
        return;
    }

    float (*sgw)[DD] = (float (*)[DD])smem;
    for (int i = tid; i < EE * DD; i += 256) sgw[i >> 10][i & 1023] = gw[i];
    __syncthreads();

    const int wave = tid >> 6, lane = tid & 63;
    const int gwave = bid * 4 + wave;
    const int nwaves = GATE_BLOCKS * 4;

    float pa_acc = 0.f, z_acc = 0.f;
    float P_acc[EE] = {0}, p6_acc[EE] = {0};
    int n1_acc[EE] = {0};

    for (int t = gwave; t < TT; t += nwaves) {
        float acc[EE] = {0};
        const float* xr = x + (size_t)t * DD;
        __bf16* xbr = xb + (size_t)t * DD;
        #pragma unroll
        for (int i = 0; i < DD / 64; ++i) {
            const float xv = xr[lane + 64 * i];
            xbr[lane + 64 * i] = (__bf16)xv;
            #pragma unroll
            for (int e = 0; e < EE; ++e) acc[e] += xv * sgw[e][lane + 64 * i];
        }
        #pragma unroll
        for (int e = 0; e < EE; ++e) {
            float v = acc[e];
            #pragma unroll
            for (int off = 32; off > 0; off >>= 1) v += __shfl_xor(v, off, 64);
            acc[e] = v;
        }
        if (lane == 0) {
            float mx = acc[0];
            #pragma unroll
            for (int e = 1; e < EE; ++e) mx = fmaxf(mx, acc[e]);
            float pr[EE], p6[EE], se = 0.f, s6 = 0.f;
            #pragma unroll
            for (int e = 0; e < EE; ++e) {
                pr[e] = __expf(acc[e] - mx); se += pr[e];
                p6[e] = __expf((acc[e] - mx) * (1.0f / 1.66f)); s6 += p6[e];
            }
            const float lse = mx + __logf(se);
            z_acc += lse * lse;
            const float ise = 1.f / se, is6 = 1.f / s6;
            #pragma unroll
            for (int e = 0; e < EE; ++e) {
                pr[e] *= ise; p6[e] *= is6;
                P_acc[e] += pr[e]; p6_acc[e] += p6[e];
                pa_acc += p6[e] * (1.f - p6[e]);
            }
            int a = 0;
            #pragma unroll
            for (int e = 1; e < EE; ++e) if (pr[e] > pr[a]) a = e;
            int b = (a == 0) ? 1 : 0;
            #pragma unroll
            for (int e = 0; e < EE; ++e) if (e != a && pr[e] > pr[b]) b = e;
            n1_acc[a]++;
            const float ga = pr[a], gb = pr[b], idn = 1.f / (ga + gb);
            e1o[t] = a; e2o[t] = b;
            g1o[t] = ga * idn; g2o[t] = gb * idn;
        }
    }
    if (lane == 0) {
        wp[wave][0] = pa_acc; wp[wave][1] = z_acc;
        #pragma unroll
        for (int e = 0; e < EE; ++e) {
            wp[wave][2 + e] = P_acc[e]; wp[wave][10 + e] = p6_acc[e];
            wp[wave][18 + e] = (float)n1_acc[e];
        }
    }
    __syncthreads();
    if (tid < 26) {
        const float s = wp[0][tid] + wp[1][tid] + wp[2][tid] + wp[3][tid];
        atomicAdd(&sums[tid], s);
    }
}

// ---------------- parallel ordered capacity scan: 16 blocks (slot, expert) --
__global__ __launch_bounds__(256) void moe_scan_kernel(
    const int* __restrict__ e1i, const int* __restrict__ e2i,
    const float* __restrict__ g1i, const float* __restrict__ g2i,
    const float* __restrict__ rnd, const float* __restrict__ sums,
    int* __restrict__ etok, int* __restrict__ p1o, int* __restrict__ p2o,
    int* __restrict__ cnt1, int* __restrict__ cnt2,
    float* __restrict__ imp1, float* __restrict__ imp2)
{
    const int bid = blockIdx.x, slot = bid >> 3, e = bid & 7;
    const int tid = threadIdx.x, wave = tid >> 6, lane = tid & 63;
    __shared__ int wtA[4], wtB[4];
    __shared__ float red[256];
    const int* ev = slot ? e2i : e1i;
    const float* gv = slot ? g2i : g1i;
    int* po = slot ? p2o : p1o;
    const int base = slot ? min((int)sums[18 + e], CAPV) : 0;

    int runTot = 0, runM = 0;
    float limp = 0.f;
    for (int c = 0; c < TT / 256; ++c) {
        const int t = c * 256 + tid;
        const int sel = (ev[t] == e) ? 1 : 0;
        const float w = gv[t];
        int ps = sel;
        #pragma unroll
        for (int off = 1; off < 64; off <<= 1) { int v = __shfl_up(ps, off, 64); if (lane >= off) ps += v; }
        if (lane == 63) wtA[wave] = ps;
        __syncthreads();
        int wpre = 0, ctot = 0;
        #pragma unroll
        for (int ww = 0; ww < 4; ++ww) { if (ww < wave) wpre += wtA[ww]; ctot += wtA[ww]; }
        const int pos = runTot + wpre + ps - 1;      // valid when sel
        int m, idx;
        if (slot == 0) {
            m = sel && (pos < CAPV);
            idx = pos;
        } else {
            m = (sel && (pos < CAPV) && (rnd[t] < 2.f * w)) ? 1 : 0;
            int pm = m;
            #pragma unroll
            for (int off = 1; off < 64; off <<= 1) { int v = __shfl_up(pm, off, 64); if (lane >= off) pm += v; }
            if (lane == 63) wtB[wave] = pm;
            __syncthreads();
            int wpm = 0, mtot = 0;
            #pragma unroll
            for (int ww = 0; ww < 4; ++ww) { if (ww < wave) wpm += wtB[ww]; mtot += wtB[ww]; }
            idx = runM + wpm + pm - 1;
            runM += mtot;
        }
        if (sel) po[t] = m ? (e * LIST_STRIDE + base + idx) : -1;
        if (m) {
            etok[e * LIST_STRIDE + base + idx] = t;
            limp += w;
        }
        runTot += ctot;
        __syncthreads();
    }
    red[tid] = limp; __syncthreads();
    for (int s = 128; s > 0; s >>= 1) { if (tid < s) red[tid] += red[tid + s]; __syncthreads(); }
    if (tid == 0) {
        if (slot == 0) { cnt1[e] = min(runTot, CAPV); imp1[e] = red[0]; }
        else           { cnt2[e] = runM;              imp2[e] = red[0]; }
    }
}

// ---------------- FFN pass 1 (R1-verified: 256x256/BK64, counted vmcnt) -----
// H = gelu(Xg @ W1 + b1). 8 waves (2Mx4N), 128 KiB LDS dbuf, depth-2 prefetch:
// stage tile t+2 after read-release barrier, s_waitcnt vmcnt(8) keeps t+2's 8
// loads in flight across tile t+1's compute (never vmcnt(0) in loop).
// LDS swizzle: logical k-chunk lc stored at phys chunk lc^(row&7) via
// pre-swizzled global source (gl_lds dest is linear); reads XOR the same key.
__global__ __launch_bounds__(512, 2) void moe_ffn1_mfma(
    const __bf16* __restrict__ xb, const __bf16* __restrict__ w1T,
    const float* __restrict__ b1, const int* __restrict__ etok,
    const int* __restrict__ cnt1, const int* __restrict__ cnt2,
    __bf16* __restrict__ H)
{
    const int f = blockIdx.x;                        // 2048 blocks
    const int xcd = f & 7, s = f >> 3;               // s in [0,256)
    const int g = xcd * 16 + (s >> 4);               // 128 groups = (e, n-tile)
    const int e = g >> 4, n0 = (g & 15) * 256;
    const int m0 = (s & 15) * 256;
    const int ce = cnt1[e] + cnt2[e];
    if (m0 >= ce) return;
    const int tid = threadIdx.x, lane = tid & 63, w = tid >> 6;
    const int wm = w >> 2, wn = w & 3;
    const int quad = lane >> 4, l16 = lane & 15;

    __shared__ __bf16 As[2][16384];   // 2 x 32 KB
    __shared__ __bf16 Bs[2][16384];   // 2 x 32 KB  (128 KiB total, 1 block/CU)

    const int srow = tid >> 3;
    const int srcoff = ((tid & 7) ^ (srow & 7)) * 8;  // pre-swizzled source
    const __bf16* ap[4];
    const __bf16* bp[4];
    const __bf16* bbase = w1T + (size_t)e * FF * DD;
    #pragma unroll
    for (int r = 0; r < 4; ++r) {
        const int gr = m0 + r * 64 + srow;
        const int tok = (gr < ce) ? etok[e * LIST_STRIDE + gr] : 0;
        ap[r] = xb + (size_t)tok * DD + srcoff;
        bp[r] = bbase + (size_t)(n0 + r * 64 + srow) * DD + srcoff;
    }
    const int ldst = w * 512;                         // wave slice (elems)

    floatx4 acc[8][4];
    #pragma unroll
    for (int i = 0; i < 8; ++i)
        #pragma unroll
        for (int j = 0; j < 4; ++j) acc[i][j] = floatx4{0.f, 0.f, 0.f, 0.f};

    const int abase  = (wm * 128 + l16) * 64;
    const int bbase2 = (wn * 64 + l16) * 64;
    const int sw0 = (quad ^ (l16 & 7)) * 8;           // kh=0 phys chunk
    const int sw1 = ((4 + quad) ^ (l16 & 7)) * 8;     // kh=1 phys chunk

    auto stage = [&](int bufi, int koff) {
        #pragma unroll
        for (int r = 0; r < 4; ++r)
            gl_lds16(ap[r] + koff, &As[bufi][r * 4096 + ldst]);
        #pragma unroll
        for (int r = 0; r < 4; ++r)
            gl_lds16(bp[r] + koff, &Bs[bufi][r * 4096 + ldst]);
    };
    auto compute = [&](int bufi) {
        bf16x8 bfr[4][2];                              // B read once, held
        #pragma unroll
        for (int j = 0; j < 4; ++j) {
            bfr[j][0] = *(const bf16x8*)&Bs[bufi][bbase2 + j * 1024 + sw0];
            bfr[j][1] = *(const bf16x8*)&Bs[bufi][bbase2 + j * 1024 + sw1];
        }
        #pragma unroll
        for (int mh = 0; mh < 2; ++mh) {
            bf16x8 av[4][2];
            #pragma unroll
            for (int i2 = 0; i2 < 4; ++i2) {
                av[i2][0] = *(const bf16x8*)&As[bufi][abase + (mh * 4 + i2) * 1024 + sw0];
                av[i2][1] = *(const bf16x8*)&As[bufi][abase + (mh * 4 + i2) * 1024 + sw1];
            }
            #pragma unroll
            for (int i2 = 0; i2 < 4; ++i2)
                #pragma unroll
                for (int j = 0; j < 4; ++j) {
                    floatx4 c = acc[mh * 4 + i2][j];
                    c = __builtin_amdgcn_mfma_f32_16x16x32_bf16(bfr[j][0], av[i2][0], c, 0, 0, 0);
                    c = __builtin_amdgcn_mfma_f32_16x16x32_bf16(bfr[j][1], av[i2][1], c, 0, 0, 0);
                    acc[mh * 4 + i2][j] = c;
                }
        }
    };

    stage(0, 0);
    stage(1, 64);
    asm volatile("s_waitcnt vmcnt(8)" ::: "memory");   // tile 0 resident
    __builtin_amdgcn_s_barrier();

    #pragma unroll 2
    for (int t = 0; t < 16; ++t) {                     // K = 1024 / 64
        const int cur = t & 1;
        compute(cur);
        asm volatile("s_waitcnt lgkmcnt(0)" ::: "memory");  // my reads retired
        __builtin_amdgcn_s_barrier();                  // all waves done w/ buf[cur]
        if (t < 14) {
            stage(cur, (t + 2) * 64);                  // depth-2 prefetch
            asm volatile("s_waitcnt vmcnt(8)" ::: "memory"); // tile t+1 resident
        } else {
            asm volatile("s_waitcnt vmcnt(0)" ::: "memory"); // tail drain
        }
        __builtin_amdgcn_s_barrier();
    }

    // epilogue: bias + gelu, 8B stores
    const float* b1e = b1 + (size_t)e * FF;
    #pragma unroll
    for (int i = 0; i < 8; ++i) {
        const int mrow = m0 + wm * 128 + i * 16 + l16;
        __bf16* hrow = H + ((size_t)e * LIST_STRIDE + mrow) * FF;
        #pragma unroll
        for (int j = 0; j < 4; ++j) {
            const int col0 = n0 + wn * 64 + j * 16 + quad * 4;
            const float4 bb = *(const float4*)&b1e[col0];
            float vv[4] = {acc[i][j][0] + bb.x, acc[i][j][1] + bb.y,
                           acc[i][j][2] + bb.z, acc[i][j][3] + bb.w};
            bf16x4 pk;
            #pragma unroll
            for (int r = 0; r < 4; ++r) {
                const float v = vv[r];
                const float u = 0.7978845608028654f * (v + 0.044715f * v * v * v);
                const float th = 1.f - 2.f / (__expf(2.f * u) + 1.f);
                pk[r] = (__bf16)(0.5f * v * (1.f + th));
            }
            *(bf16x4*)&hrow[col0] = pk;
        }
    }
}

// ---------------- FFN pass 2 (R1-verified, K = FF = 4096) -------------------
__global__ __launch_bounds__(512, 2) void moe_ffn2_mfma(
    const __bf16* __restrict__ H, const __bf16* __restrict__ w2T,
    const float* __restrict__ b2, const int* __restrict__ cnt1,
    const int* __restrict__ cnt2, __bf16* __restrict__ O)
{
    const int f = blockIdx.x;                        // 512 blocks
    const int xcd = f & 7, s = f >> 3;               // s in [0,64)
    const int g = xcd * 4 + (s >> 4);                // 32 groups = (e, n-tile)
    const int e = g >> 2, n0 = (g & 3) * 256;
    const int m0 = (s & 15) * 256;
    const int ce = cnt1[e] + cnt2[e];
    if (m0 >= ce) return;
    const int tid = threadIdx.x, lane = tid & 63, w = tid >> 6;
    const int wm = w >> 2, wn = w & 3;
    const int quad = lane >> 4, l16 = lane & 15;

    __shared__ __bf16 As[2][16384];
    __shared__ __bf16 Bs[2][16384];

    const int srow = tid >> 3;
    const int srcoff = ((tid & 7) ^ (srow & 7)) * 8;
    const __bf16* ap[4];
    const __bf16* bp[4];
    const __bf16* bbase = w2T + (size_t)e * DD * FF;
    #pragma unroll
    for (int r = 0; r < 4; ++r) {
        ap[r] = H + ((size_t)e * LIST_STRIDE + m0 + r * 64 + srow) * FF + srcoff;
        bp[r] = bbase + (size_t)(n0 + r * 64 + srow) * FF + srcoff;
    }
    const int ldst = w * 512;

    floatx4 acc[8][4];
    #pragma unroll
    for (int i = 0; i < 8; ++i)
        #pragma unroll
        for (int j = 0; j < 4; ++j) acc[i][j] = floatx4{0.f, 0.f, 0.f, 0.f};

    const int abase  = (wm * 128 + l16) * 64;
    const int bbase2 = (wn * 64 + l16) * 64;
    const int sw0 = (quad ^ (l16 & 7)) * 8;
    const int sw1 = ((4 + quad) ^ (l16 & 7)) * 8;

    auto stage = [&](int bufi, int koff) {
        #pragma unroll
        for (int r = 0; r < 4; ++r)
            gl_lds16(ap[r] + koff, &As[bufi][r * 4096 + ldst]);
        #pragma unroll
        for (int r = 0; r < 4; ++r)
            gl_lds16(bp[r] + koff, &Bs[bufi][r * 4096 + ldst]);
    };
    auto compute = [&](int bufi) {
        bf16x8 bfr[4][2];
        #pragma unroll
        for (int j = 0; j < 4; ++j) {
            bfr[j][0] = *(const bf16x8*)&Bs[bufi][bbase2 + j * 1024 + sw0];
            bfr[j][1] = *(const bf16x8*)&Bs[bufi][bbase2 + j * 1024 + sw1];
        }
        #pragma unroll
        for (int mh = 0; mh < 2; ++mh) {
            bf16x8 av[4][2];
            #pragma unroll
            for (int i2 = 0; i2 < 4; ++i2) {
                av[i2][0] = *(const bf16x8*)&As[bufi][abase + (mh * 4 + i2) * 1024 + sw0];
                av[i2][1] = *(const bf16x8*)&As[bufi][abase + (mh * 4 + i2) * 1024 + sw1];
            }
            #pragma unroll
            for (int i2 = 0; i2 < 4; ++i2)
                #pragma unroll
                for (int j = 0; j < 4; ++j) {
                    floatx4 c = acc[mh * 4 + i2][j];
                    c = __builtin_amdgcn_mfma_f32_16x16x32_bf16(bfr[j][0], av[i2][0], c, 0, 0, 0);
                    c = __builtin_amdgcn_mfma_f32_16x16x32_bf16(bfr[j][1], av[i2][1], c, 0, 0, 0);
                    acc[mh * 4 + i2][j] = c;
                }
        }
    };

    stage(0, 0);
    stage(1, 64);
    asm volatile("s_waitcnt vmcnt(8)" ::: "memory");
    __builtin_amdgcn_s_barrier();

    #pragma unroll 2
    for (int t = 0; t < 64; ++t) {                    // K = 4096 / 64
        const int cur = t & 1;
        compute(cur);
        asm volatile("s_waitcnt lgkmcnt(0)" ::: "memory");
        __builtin_amdgcn_s_barrier();
        if (t < 62) {
            stage(cur, (t + 2) * 64);
            asm volatile("s_waitcnt vmcnt(8)" ::: "memory");
        } else {
            asm volatile("s_waitcnt vmcnt(0)" ::: "memory");
        }
        __builtin_amdgcn_s_barrier();
    }

    const float* b2e = b2 + (size_t)e * DD;
    #pragma unroll
    for (int i = 0; i < 8; ++i) {
        const int grow = m0 + wm * 128 + i * 16 + l16;
        if (grow < ce) {
            __bf16* orow = O + ((size_t)e * LIST_STRIDE + grow) * DD;
            #pragma unroll
            for (int j = 0; j < 4; ++j) {
                const int col0 = n0 + wn * 64 + j * 16 + quad * 4;
                const float4 bb = *(const float4*)&b2e[col0];
                bf16x4 pk;
                pk[0] = (__bf16)(acc[i][j][0] + bb.x);
                pk[1] = (__bf16)(acc[i][j][1] + bb.y);
                pk[2] = (__bf16)(acc[i][j][2] + bb.z);
                pk[3] = (__bf16)(acc[i][j][3] + bb.w);
                *(bf16x4*)&orow[col0] = pk;
            }
        }
    }
}

// ---------------- combine (+ aux folded into block 0 / thread 0) ------------
__global__ __launch_bounds__(256) void moe_combine_kernel(
    const __bf16* __restrict__ O, const float* __restrict__ g1v,
    const float* __restrict__ g2v, const int* __restrict__ p1v,
    const int* __restrict__ p2v, float* __restrict__ y,
    const float* __restrict__ sums,
    const float* __restrict__ imp1, const float* __restrict__ imp2)
{
    const int t = blockIdx.x;
    if (t == 0 && threadIdx.x == 0) {
        const float invT = 1.f / (float)TT;
        const float pa = sums[0] / ((float)TT * (float)EE);
        float pb = 0.f, load = 0.f, msum = 0.f;
        float im[EE];
        for (int e = 0; e < EE; ++e) {
            const float pm = sums[10 + e] * invT;
            pb += pm * (1.f - pm);
            load += (sums[18 + e] * invT) * (sums[2 + e] * invT);
            im[e] = imp1[e] + imp2[e];
            msum += im[e];
        }
        pb = 1.f / (float)EE - pb / (float)EE;
        const float penalty = 0.01f * (pa + pb);
        const float z_loss = 0.001f * sums[1] * invT;
        const float load_loss = 0.01f * (float)EE * load;
        const float mean = msum / (float)EE;
        float var = 0.f;
        for (int e = 0; e < EE; ++e) { const float d = im[e] - mean; var += d * d; }
        var /= (float)EE;
        const float imp_loss = 0.01f * var / (mean * mean);
        y[(size_t)TT * DD] = penalty + z_loss + load_loss + imp_loss;
    }
    const int col = threadIdx.x * 4;
    const int p1 = p1v[t], p2 = p2v[t];
    float4 r = make_float4(0.f, 0.f, 0.f, 0.f);
    if (p1 >= 0) {
        const float g = g1v[t];
        const bf16x4 v = *(const bf16x4*)&O[(size_t)p1 * DD + col];
        r.x += g * (float)v[0]; r.y += g * (float)v[1];
        r.z += g * (float)v[2]; r.w += g * (float)v[3];
    }
    if (p2 >= 0) {
        const float g = g2v[t];
        const bf16x4 v = *(const bf16x4*)&O[(size_t)p2 * DD + col];
        r.x += g * (float)v[0]; r.y += g * (float)v[1];
        r.z += g * (float)v[2]; r.w += g * (float)v[3];
    }
    *(float4*)&y[(size_t)t * DD + col] = r;
}

// ---------------- launch ----------------------------------------------------
extern "C" void kernel_launch(void* const* d_in, const int* in_sizes, int n_in,
                              void* d_out, int out_size, void* d_ws, size_t ws_size,
                              hipStream_t stream) {
    const float* x   = (const float*)d_in[0];
    const float* gw  = (const float*)d_in[1];
    const float* w1  = (const float*)d_in[2];
    const float* b1  = (const float*)d_in[3];
    const float* w2  = (const float*)d_in[4];
    const float* b2  = (const float*)d_in[5];
    const float* rnd = (const float*)d_in[6];
    float* out = (float*)d_out;

    char* p = (char*)d_ws;
    float* sums = (float*)p;                 // 26 floats
    float* imp1 = (float*)(p + 128);         // 8 floats
    float* imp2 = (float*)(p + 160);         // 8 floats
    int*   cnt1 = (int*)(p + 192);           // 8 ints
    int*   cnt2 = (int*)(p + 224);           // 8 ints
    p += 512;
    int*   e1v = (int*)p;   p += TT * 4;
    int*   e2v = (int*)p;   p += TT * 4;
    float* g1v = (float*)p; p += TT * 4;
    float* g2v = (float*)p; p += TT * 4;
    int*   p1v = (int*)p;   p += TT * 4;
    int*   p2v = (int*)p;   p += TT * 4;
    int*   etok = (int*)p;  p += EE * LIST_STRIDE * 4;
    uintptr_t q = (((uintptr_t)p) + 255) & ~(uintptr_t)255;
    __bf16* xb  = (__bf16*)q;  q += (size_t)TT * DD * 2;             // 16 MB
    __bf16* w1T = (__bf16*)q;  q += (size_t)EE * FF * DD * 2;        // 64 MB
    __bf16* w2T = (__bf16*)q;  q += (size_t)EE * DD * FF * 2;        // 64 MB
    __bf16* H   = (__bf16*)q;  q += (size_t)EE * LIST_STRIDE * FF * 2; // 256 MB
    __bf16* O   = (__bf16*)q;                                        // 64 MB

    hipMemsetAsync(sums, 0, 128, stream);

    moe_prep_kernel<<<GATE_BLOCKS + T1_BLOCKS + T2_BLOCKS, 256, 0, stream>>>(
        x, gw, e1v, e2v, g1v, g2v, sums, xb, w1, w1T, w2, w2T);
    moe_scan_kernel<<<16, 256, 0, stream>>>(e1v, e2v, g1v, g2v, rnd, sums,
                                            etok, p1v, p2v, cnt1, cnt2, imp1, imp2);

    moe_ffn1_mfma<<<2048, 512, 0, stream>>>(xb, w1T, b1, etok, cnt1, cnt2, H);
    moe_ffn2_mfma<<<512, 512, 0, stream>>>(H, w2T, b2, cnt1, cnt2, O);
    moe_combine_kernel<<<TT, 256, 0, stream>>>(O, g1v, g2v, p1v, p2v, out,
                                               sums, imp1, imp2);
}

// Round 9
// 695.602 us; speedup vs baseline: 1.1349x; 1.0181x over previous
//
#include <hip/hip_runtime.h>
#include <math.h>
#include <stdint.h>

#define DD 1024
#define EE 8
#define FF 4096
#define CAPV 2048
#define TT 8192
#define LIST_STRIDE 4096   // per-expert entry capacity (2*CAP)

typedef __bf16 bf16x8 __attribute__((ext_vector_type(8)));
typedef __bf16 bf16x4 __attribute__((ext_vector_type(4)));
typedef float floatx4 __attribute__((ext_vector_type(4)));

typedef __attribute__((address_space(3))) unsigned int as3_uint;
typedef __attribute__((address_space(1))) const unsigned int as1_uint;

__device__ __forceinline__ void gl_lds16(const void* g, void* l) {
    __builtin_amdgcn_global_load_lds((as1_uint*)g, (as3_uint*)l, 16, 0, 0);
}

__device__ __forceinline__ unsigned short f2bf(float f) {
    union { float f; unsigned int u; } v; v.f = f;
    const unsigned int r = v.u + 0x7FFFu + ((v.u >> 16) & 1u);
    return (unsigned short)(r >> 16);
}

// ---------------- fused prep: gate (blocks 0..255) + w1/w2 transpose --------
// sums layout: [0]=pa [1]=z [2..9]=P [10..17]=p6 [18..25]=n1 counts (as float)
#define GATE_BLOCKS 256
#define T1_BLOCKS 4096    // (DD/128=8) x (FF/64=64) x 8
#define T2_BLOCKS 4096    // (FF/128=32) x (DD/64=16) x 8

// fp32 [K x N] -> bf16 [N x K] transpose, 128k x 64n tile.
// Global: float4 reads (256B contiguous per row segment), dword writes
// (256B contiguous per n-row). LDS: logical (r,c) stored at phys column
// (c + ((r&1)<<5) + (r>>1)) & 63 -> both store and read phases are 2-way
// bank access (free, m136).
__device__ __forceinline__ void transpose_body128(
    const float* __restrict__ in, __bf16* __restrict__ out,
    int K, int N, int bk, int bn, int e, float* tile, int tid)
{
    const float* ine = in + (size_t)e * K * N;
    __bf16* oute = out + (size_t)e * K * N;
    #pragma unroll
    for (int p = 0; p < 8; ++p) {
        const int idx = p * 256 + tid;          // 0..2047
        const int r = idx >> 4, c4 = (idx & 15) * 4;
        const float4 v = *(const float4*)&ine[(size_t)(bk + r) * N + bn + c4];
        const int rot = ((r & 1) << 5) + (r >> 1);
        float vv[4] = {v.x, v.y, v.z, v.w};
        #pragma unroll
        for (int j = 0; j < 4; ++j)
            tile[r * 64 + ((c4 + j + rot) & 63)] = vv[j];
    }
    __syncthreads();
    #pragma unroll
    for (int q = 0; q < 16; ++q) {
        const int wdx = q * 256 + tid;          // 0..4095
        const int nl = wdx >> 6, kp = (wdx & 63) * 2;
        const int t2 = kp >> 1;
        const float lo = tile[kp * 64 + ((nl + t2) & 63)];
        const float hi = tile[(kp + 1) * 64 + ((nl + 32 + t2) & 63)];
        const unsigned int pk = (unsigned int)f2bf(lo) | ((unsigned int)f2bf(hi) << 16);
        *(unsigned int*)&oute[(size_t)(bn + nl) * K + bk + kp] = pk;
    }
}

__global__ __launch_bounds__(256) void moe_prep_kernel(
    const float* __restrict__ x, const float* __restrict__ gw,
    int* __restrict__ e1o, int* __restrict__ e2o,
    float* __restrict__ g1o, float* __restrict__ g2o,
    float* __restrict__ sums, __bf16* __restrict__ xb,
    const float* __restrict__ w1, __bf16* __restrict__ w1T,
    const float* __restrict__ w2, __bf16* __restrict__ w2T)
{
    __shared__ float smem[EE * DD];        // 32 KB (gate gw / transpose tile)
    __shared__ float wp[4][26];
    const int bid = blockIdx.x;
    const int tid = threadIdx.x;

    if (bid >= GATE_BLOCKS) {
        if (bid < GATE_BLOCKS + T1_BLOCKS) {
            const int f = bid - GATE_BLOCKS;            // w1: K=DD, N=FF
            transpose_body128(w1, w1T, DD, FF, (f & 7) * 128,
                              ((f >> 3) & 63) * 64, f >> 9, smem, tid);
        } else {
            const int f = bid - GATE_BLOCKS - T1_BLOCKS; // w2: K=FF, N=DD
            transpose_body128(w2, w2T, FF, DD, (f & 31) * 128,
                              ((f >> 5) & 15) * 64, f >> 9, smem, tid);
        }
        return;
    }

    float (*sgw)[DD] = (float (*)[DD])smem;
    for (int i = tid; i < EE * DD; i += 256) sgw[i >> 10][i & 1023] = gw[i];
    __syncthreads();

    const int wave = tid >> 6, lane = tid & 63;
    const int gwave = bid * 4 + wave;
    const int nwaves = GATE_BLOCKS * 4;

    float pa_acc = 0.f, z_acc = 0.f;
    float P_acc[EE] = {0}, p6_acc[EE] = {0};
    int n1_acc[EE] = {0};

    for (int t = gwave; t < TT; t += nwaves) {
        float acc[EE] = {0};
        const float* xr = x + (size_t)t * DD;
        __bf16* xbr = xb + (size_t)t * DD;
        #pragma unroll
        for (int i = 0; i < DD / 64; ++i) {
            const float xv = xr[lane + 64 * i];
            xbr[lane + 64 * i] = (__bf16)xv;
            #pragma unroll
            for (int e = 0; e < EE; ++e) acc[e] += xv * sgw[e][lane + 64 * i];
        }
        #pragma unroll
        for (int e = 0; e < EE; ++e) {
            float v = acc[e];
            #pragma unroll
            for (int off = 32; off > 0; off >>= 1) v += __shfl_xor(v, off, 64);
            acc[e] = v;
        }
        if (lane == 0) {
            float mx = acc[0];
            #pragma unroll
            for (int e = 1; e < EE; ++e) mx = fmaxf(mx, acc[e]);
            float pr[EE], p6[EE], se = 0.f, s6 = 0.f;
            #pragma unroll
            for (int e = 0; e < EE; ++e) {
                pr[e] = __expf(acc[e] - mx); se += pr[e];
                p6[e] = __expf((acc[e] - mx) * (1.0f / 1.66f)); s6 += p6[e];
            }
            const float lse = mx + __logf(se);
            z_acc += lse * lse;
            const float ise = 1.f / se, is6 = 1.f / s6;
            #pragma unroll
            for (int e = 0; e < EE; ++e) {
                pr[e] *= ise; p6[e] *= is6;
                P_acc[e] += pr[e]; p6_acc[e] += p6[e];
                pa_acc += p6[e] * (1.f - p6[e]);
            }
            int a = 0;
            #pragma unroll
            for (int e = 1; e < EE; ++e) if (pr[e] > pr[a]) a = e;
            int b = (a == 0) ? 1 : 0;
            #pragma unroll
            for (int e = 0; e < EE; ++e) if (e != a && pr[e] > pr[b]) b = e;
            n1_acc[a]++;
            const float ga = pr[a], gb = pr[b], idn = 1.f / (ga + gb);
            e1o[t] = a; e2o[t] = b;
            g1o[t] = ga * idn; g2o[t] = gb * idn;
        }
    }
    if (lane == 0) {
        wp[wave][0] = pa_acc; wp[wave][1] = z_acc;
        #pragma unroll
        for (int e = 0; e < EE; ++e) {
            wp[wave][2 + e] = P_acc[e]; wp[wave][10 + e] = p6_acc[e];
            wp[wave][18 + e] = (float)n1_acc[e];
        }
    }
    __syncthreads();
    if (tid < 26) {
        const float s = wp[0][tid] + wp[1][tid] + wp[2][tid] + wp[3][tid];
        atomicAdd(&sums[tid], s);
    }
}

// ---------------- parallel ordered capacity scan: 16 blocks (slot, expert) --
__global__ __launch_bounds__(256) void moe_scan_kernel(
    const int* __restrict__ e1i, const int* __restrict__ e2i,
    const float* __restrict__ g1i, const float* __restrict__ g2i,
    const float* __restrict__ rnd, const float* __restrict__ sums,
    int* __restrict__ etok, int* __restrict__ p1o, int* __restrict__ p2o,
    int* __restrict__ cnt1, int* __restrict__ cnt2,
    float* __restrict__ imp1, float* __restrict__ imp2)
{
    const int bid = blockIdx.x, slot = bid >> 3, e = bid & 7;
    const int tid = threadIdx.x, wave = tid >> 6, lane = tid & 63;
    __shared__ int wtA[4], wtB[4];
    __shared__ float red[256];
    const int* ev = slot ? e2i : e1i;
    const float* gv = slot ? g2i : g1i;
    int* po = slot ? p2o : p1o;
    const int base = slot ? min((int)sums[18 + e], CAPV) : 0;

    int runTot = 0, runM = 0;
    float limp = 0.f;
    for (int c = 0; c < TT / 256; ++c) {
        const int t = c * 256 + tid;
        const int sel = (ev[t] == e) ? 1 : 0;
        const float w = gv[t];
        int ps = sel;
        #pragma unroll
        for (int off = 1; off < 64; off <<= 1) { int v = __shfl_up(ps, off, 64); if (lane >= off) ps += v; }
        if (lane == 63) wtA[wave] = ps;
        __syncthreads();
        int wpre = 0, ctot = 0;
        #pragma unroll
        for (int ww = 0; ww < 4; ++ww) { if (ww < wave) wpre += wtA[ww]; ctot += wtA[ww]; }
        const int pos = runTot + wpre + ps - 1;      // valid when sel
        int m, idx;
        if (slot == 0) {
            m = sel && (pos < CAPV);
            idx = pos;
        } else {
            m = (sel && (pos < CAPV) && (rnd[t] < 2.f * w)) ? 1 : 0;
            int pm = m;
            #pragma unroll
            for (int off = 1; off < 64; off <<= 1) { int v = __shfl_up(pm, off, 64); if (lane >= off) pm += v; }
            if (lane == 63) wtB[wave] = pm;
            __syncthreads();
            int wpm = 0, mtot = 0;
            #pragma unroll
            for (int ww = 0; ww < 4; ++ww) { if (ww < wave) wpm += wtB[ww]; mtot += wtB[ww]; }
            idx = runM + wpm + pm - 1;
            runM += mtot;
        }
        if (sel) po[t] = m ? (e * LIST_STRIDE + base + idx) : -1;
        if (m) {
            etok[e * LIST_STRIDE + base + idx] = t;
            limp += w;
        }
        runTot += ctot;
        __syncthreads();
    }
    red[tid] = limp; __syncthreads();
    for (int s = 128; s > 0; s >>= 1) { if (tid < s) red[tid] += red[tid + s]; __syncthreads(); }
    if (tid == 0) {
        if (slot == 0) { cnt1[e] = min(runTot, CAPV); imp1[e] = red[0]; }
        else           { cnt2[e] = runM;              imp2[e] = red[0]; }
    }
}

// ---------------- FFN pass 1 (R1-verified: 256x256/BK64, counted vmcnt) -----
// H = gelu(Xg @ W1 + b1). 8 waves (2Mx4N), 128 KiB LDS dbuf, depth-2 prefetch:
// stage tile t+2 after read-release barrier, s_waitcnt vmcnt(8) keeps t+2's 8
// loads in flight across tile t+1's compute (never vmcnt(0) in loop).
__global__ __launch_bounds__(512, 2) void moe_ffn1_mfma(
    const __bf16* __restrict__ xb, const __bf16* __restrict__ w1T,
    const float* __restrict__ b1, const int* __restrict__ etok,
    const int* __restrict__ cnt1, const int* __restrict__ cnt2,
    __bf16* __restrict__ H)
{
    const int f = blockIdx.x;                        // 2048 blocks
    const int xcd = f & 7, s = f >> 3;               // s in [0,256)
    const int g = xcd * 16 + (s >> 4);               // 128 groups = (e, n-tile)
    const int e = g >> 4, n0 = (g & 15) * 256;
    const int m0 = (s & 15) * 256;
    const int ce = cnt1[e] + cnt2[e];
    if (m0 >= ce) return;
    const int tid = threadIdx.x, lane = tid & 63, w = tid >> 6;
    const int wm = w >> 2, wn = w & 3;
    const int quad = lane >> 4, l16 = lane & 15;

    __shared__ __bf16 As[2][16384];   // 2 x 32 KB
    __shared__ __bf16 Bs[2][16384];   // 2 x 32 KB  (128 KiB total, 1 block/CU)

    const int srow = tid >> 3;
    const int srcoff = ((tid & 7) ^ (srow & 7)) * 8;  // pre-swizzled source
    const __bf16* ap[4];
    const __bf16* bp[4];
    const __bf16* bbase = w1T + (size_t)e * FF * DD;
    #pragma unroll
    for (int r = 0; r < 4; ++r) {
        const int gr = m0 + r * 64 + srow;
        const int tok = (gr < ce) ? etok[e * LIST_STRIDE + gr] : 0;
        ap[r] = xb + (size_t)tok * DD + srcoff;
        bp[r] = bbase + (size_t)(n0 + r * 64 + srow) * DD + srcoff;
    }
    const int ldst = w * 512;                         // wave slice (elems)

    floatx4 acc[8][4];
    #pragma unroll
    for (int i = 0; i < 8; ++i)
        #pragma unroll
        for (int j = 0; j < 4; ++j) acc[i][j] = floatx4{0.f, 0.f, 0.f, 0.f};

    const int abase  = (wm * 128 + l16) * 64;
    const int bbase2 = (wn * 64 + l16) * 64;
    const int sw0 = (quad ^ (l16 & 7)) * 8;           // kh=0 phys chunk
    const int sw1 = ((4 + quad) ^ (l16 & 7)) * 8;     // kh=1 phys chunk

    auto stage = [&](int bufi, int koff) {
        #pragma unroll
        for (int r = 0; r < 4; ++r)
            gl_lds16(ap[r] + koff, &As[bufi][r * 4096 + ldst]);
        #pragma unroll
        for (int r = 0; r < 4; ++r)
            gl_lds16(bp[r] + koff, &Bs[bufi][r * 4096 + ldst]);
    };
    auto compute = [&](int bufi) {
        bf16x8 bfr[4][2];                              // B read once, held
        #pragma unroll
        for (int j = 0; j < 4; ++j) {
            bfr[j][0] = *(const bf16x8*)&Bs[bufi][bbase2 + j * 1024 + sw0];
            bfr[j][1] = *(const bf16x8*)&Bs[bufi][bbase2 + j * 1024 + sw1];
        }
        #pragma unroll
        for (int mh = 0; mh < 2; ++mh) {
            bf16x8 av[4][2];
            #pragma unroll
            for (int i2 = 0; i2 < 4; ++i2) {
                av[i2][0] = *(const bf16x8*)&As[bufi][abase + (mh * 4 + i2) * 1024 + sw0];
                av[i2][1] = *(const bf16x8*)&As[bufi][abase + (mh * 4 + i2) * 1024 + sw1];
            }
            #pragma unroll
            for (int i2 = 0; i2 < 4; ++i2)
                #pragma unroll
                for (int j = 0; j < 4; ++j) {
                    floatx4 c = acc[mh * 4 + i2][j];
                    c = __builtin_amdgcn_mfma_f32_16x16x32_bf16(bfr[j][0], av[i2][0], c, 0, 0, 0);
                    c = __builtin_amdgcn_mfma_f32_16x16x32_bf16(bfr[j][1], av[i2][1], c, 0, 0, 0);
                    acc[mh * 4 + i2][j] = c;
                }
        }
    };

    stage(0, 0);
    stage(1, 64);
    asm volatile("s_waitcnt vmcnt(8)" ::: "memory");   // tile 0 resident
    __builtin_amdgcn_s_barrier();

    #pragma unroll 2
    for (int t = 0; t < 16; ++t) {                     // K = 1024 / 64
        const int cur = t & 1;
        compute(cur);
        asm volatile("s_waitcnt lgkmcnt(0)" ::: "memory");  // my reads retired
        __builtin_amdgcn_s_barrier();                  // all waves done w/ buf[cur]
        if (t < 14) {
            stage(cur, (t + 2) * 64);                  // depth-2 prefetch
            asm volatile("s_waitcnt vmcnt(8)" ::: "memory"); // tile t+1 resident
        } else {
            asm volatile("s_waitcnt vmcnt(0)" ::: "memory"); // tail drain
        }
        __builtin_amdgcn_s_barrier();
    }

    // epilogue: bias + gelu, 8B stores
    const float* b1e = b1 + (size_t)e * FF;
    #pragma unroll
    for (int i = 0; i < 8; ++i) {
        const int mrow = m0 + wm * 128 + i * 16 + l16;
        __bf16* hrow = H + ((size_t)e * LIST_STRIDE + mrow) * FF;
        #pragma unroll
        for (int j = 0; j < 4; ++j) {
            const int col0 = n0 + wn * 64 + j * 16 + quad * 4;
            const float4 bb = *(const float4*)&b1e[col0];
            float vv[4] = {acc[i][j][0] + bb.x, acc[i][j][1] + bb.y,
                           acc[i][j][2] + bb.z, acc[i][j][3] + bb.w};
            bf16x4 pk;
            #pragma unroll
            for (int r = 0; r < 4; ++r) {
                const float v = vv[r];
                const float u = 0.7978845608028654f * (v + 0.044715f * v * v * v);
                const float th = 1.f - 2.f / (__expf(2.f * u) + 1.f);
                pk[r] = (__bf16)(0.5f * v * (1.f + th));
            }
            *(bf16x4*)&hrow[col0] = pk;
        }
    }
}

// ---------------- FFN pass 2 (R1-verified, K = FF = 4096) -------------------
__global__ __launch_bounds__(512, 2) void moe_ffn2_mfma(
    const __bf16* __restrict__ H, const __bf16* __restrict__ w2T,
    const float* __restrict__ b2, const int* __restrict__ cnt1,
    const int* __restrict__ cnt2, __bf16* __restrict__ O)
{
    const int f = blockIdx.x;                        // 512 blocks
    const int xcd = f & 7, s = f >> 3;               // s in [0,64)
    const int g = xcd * 4 + (s >> 4);                // 32 groups = (e, n-tile)
    const int e = g >> 2, n0 = (g & 3) * 256;
    const int m0 = (s & 15) * 256;
    const int ce = cnt1[e] + cnt2[e];
    if (m0 >= ce) return;
    const int tid = threadIdx.x, lane = tid & 63, w = tid >> 6;
    const int wm = w >> 2, wn = w & 3;
    const int quad = lane >> 4, l16 = lane & 15;

    __shared__ __bf16 As[2][16384];
    __shared__ __bf16 Bs[2][16384];

    const int srow = tid >> 3;
    const int srcoff = ((tid & 7) ^ (srow & 7)) * 8;
    const __bf16* ap[4];
    const __bf16* bp[4];
    const __bf16* bbase = w2T + (size_t)e * DD * FF;
    #pragma unroll
    for (int r = 0; r < 4; ++r) {
        ap[r] = H + ((size_t)e * LIST_STRIDE + m0 + r * 64 + srow) * FF + srcoff;
        bp[r] = bbase + (size_t)(n0 + r * 64 + srow) * FF + srcoff;
    }
    const int ldst = w * 512;

    floatx4 acc[8][4];
    #pragma unroll
    for (int i = 0; i < 8; ++i)
        #pragma unroll
        for (int j = 0; j < 4; ++j) acc[i][j] = floatx4{0.f, 0.f, 0.f, 0.f};

    const int abase  = (wm * 128 + l16) * 64;
    const int bbase2 = (wn * 64 + l16) * 64;
    const int sw0 = (quad ^ (l16 & 7)) * 8;
    const int sw1 = ((4 + quad) ^ (l16 & 7)) * 8;

    auto stage = [&](int bufi, int koff) {
        #pragma unroll
        for (int r = 0; r < 4; ++r)
            gl_lds16(ap[r] + koff, &As[bufi][r * 4096 + ldst]);
        #pragma unroll
        for (int r = 0; r < 4; ++r)
            gl_lds16(bp[r] + koff, &Bs[bufi][r * 4096 + ldst]);
    };
    auto compute = [&](int bufi) {
        bf16x8 bfr[4][2];
        #pragma unroll
        for (int j = 0; j < 4; ++j) {
            bfr[j][0] = *(const bf16x8*)&Bs[bufi][bbase2 + j * 1024 + sw0];
            bfr[j][1] = *(const bf16x8*)&Bs[bufi][bbase2 + j * 1024 + sw1];
        }
        #pragma unroll
        for (int mh = 0; mh < 2; ++mh) {
            bf16x8 av[4][2];
            #pragma unroll
            for (int i2 = 0; i2 < 4; ++i2) {
                av[i2][0] = *(const bf16x8*)&As[bufi][abase + (mh * 4 + i2) * 1024 + sw0];
                av[i2][1] = *(const bf16x8*)&As[bufi][abase + (mh * 4 + i2) * 1024 + sw1];
            }
            #pragma unroll
            for (int i2 = 0; i2 < 4; ++i2)
                #pragma unroll
                for (int j = 0; j < 4; ++j) {
                    floatx4 c = acc[mh * 4 + i2][j];
                    c = __builtin_amdgcn_mfma_f32_16x16x32_bf16(bfr[j][0], av[i2][0], c, 0, 0, 0);
                    c = __builtin_amdgcn_mfma_f32_16x16x32_bf16(bfr[j][1], av[i2][1], c, 0, 0, 0);
                    acc[mh * 4 + i2][j] = c;
                }
        }
    };

    stage(0, 0);
    stage(1, 64);
    asm volatile("s_waitcnt vmcnt(8)" ::: "memory");
    __builtin_amdgcn_s_barrier();

    #pragma unroll 2
    for (int t = 0; t < 64; ++t) {                    // K = 4096 / 64
        const int cur = t & 1;
        compute(cur);
        asm volatile("s_waitcnt lgkmcnt(0)" ::: "memory");
        __builtin_amdgcn_s_barrier();
        if (t < 62) {
            stage(cur, (t + 2) * 64);
            asm volatile("s_waitcnt vmcnt(8)" ::: "memory");
        } else {
            asm volatile("s_waitcnt vmcnt(0)" ::: "memory");
        }
        __builtin_amdgcn_s_barrier();
    }

    const float* b2e = b2 + (size_t)e * DD;
    #pragma unroll
    for (int i = 0; i < 8; ++i) {
        const int grow = m0 + wm * 128 + i * 16 + l16;
        if (grow < ce) {
            __bf16* orow = O + ((size_t)e * LIST_STRIDE + grow) * DD;
            #pragma unroll
            for (int j = 0; j < 4; ++j) {
                const int col0 = n0 + wn * 64 + j * 16 + quad * 4;
                const float4 bb = *(const float4*)&b2e[col0];
                bf16x4 pk;
                pk[0] = (__bf16)(acc[i][j][0] + bb.x);
                pk[1] = (__bf16)(acc[i][j][1] + bb.y);
                pk[2] = (__bf16)(acc[i][j][2] + bb.z);
                pk[3] = (__bf16)(acc[i][j][3] + bb.w);
                *(bf16x4*)&orow[col0] = pk;
            }
        }
    }
}

// ---------------- combine (+ aux folded into block 0 / thread 0) ------------
__global__ __launch_bounds__(256) void moe_combine_kernel(
    const __bf16* __restrict__ O, const float* __restrict__ g1v,
    const float* __restrict__ g2v, const int* __restrict__ p1v,
    const int* __restrict__ p2v, float* __restrict__ y,
    const float* __restrict__ sums,
    const float* __restrict__ imp1, const float* __restrict__ imp2)
{
    const int t = blockIdx.x;
    if (t == 0 && threadIdx.x == 0) {
        const float invT = 1.f / (float)TT;
        const float pa = sums[0] / ((float)TT * (float)EE);
        float pb = 0.f, load = 0.f, msum = 0.f;
        float im[EE];
        for (int e = 0; e < EE; ++e) {
            const float pm = sums[10 + e] * invT;
            pb += pm * (1.f - pm);
            load += (sums[18 + e] * invT) * (sums[2 + e] * invT);
            im[e] = imp1[e] + imp2[e];
            msum += im[e];
        }
        pb = 1.f / (float)EE - pb / (float)EE;
        const float penalty = 0.01f * (pa + pb);
        const float z_loss = 0.001f * sums[1] * invT;
        const float load_loss = 0.01f * (float)EE * load;
        const float mean = msum / (float)EE;
        float var = 0.f;
        for (int e = 0; e < EE; ++e) { const float d = im[e] - mean; var += d * d; }
        var /= (float)EE;
        const float imp_loss = 0.01f * var / (mean * mean);
        y[(size_t)TT * DD] = penalty + z_loss + load_loss + imp_loss;
    }
    const int col = threadIdx.x * 4;
    const int p1 = p1v[t], p2 = p2v[t];
    float4 r = make_float4(0.f, 0.f, 0.f, 0.f);
    if (p1 >= 0) {
        const float g = g1v[t];
        const bf16x4 v = *(const bf16x4*)&O[(size_t)p1 * DD + col];
        r.x += g * (float)v[0]; r.y += g * (float)v[1];
        r.z += g * (float)v[2]; r.w += g * (float)v[3];
    }
    if (p2 >= 0) {
        const float g = g2v[t];
        const bf16x4 v = *(const bf16x4*)&O[(size_t)p2 * DD + col];
        r.x += g * (float)v[0]; r.y += g * (float)v[1];
        r.z += g * (float)v[2]; r.w += g * (float)v[3];
    }
    *(float4*)&y[(size_t)t * DD + col] = r;
}

// ---------------- launch ----------------------------------------------------
extern "C" void kernel_launch(void* const* d_in, const int* in_sizes, int n_in,
                              void* d_out, int out_size, void* d_ws, size_t ws_size,
                              hipStream_t stream) {
    const float* x   = (const float*)d_in[0];
    const float* gw  = (const float*)d_in[1];
    const float* w1  = (const float*)d_in[2];
    const float* b1  = (const float*)d_in[3];
    const float* w2  = (const float*)d_in[4];
    const float* b2  = (const float*)d_in[5];
    const float* rnd = (const float*)d_in[6];
    float* out = (float*)d_out;

    char* p = (char*)d_ws;
    float* sums = (float*)p;                 // 26 floats
    float* imp1 = (float*)(p + 128);         // 8 floats
    float* imp2 = (float*)(p + 160);         // 8 floats
    int*   cnt1 = (int*)(p + 192);           // 8 ints
    int*   cnt2 = (int*)(p + 224);           // 8 ints
    p += 512;
    int*   e1v = (int*)p;   p += TT * 4;
    int*   e2v = (int*)p;   p += TT * 4;
    float* g1v = (float*)p; p += TT * 4;
    float* g2v = (float*)p; p += TT * 4;
    int*   p1v = (int*)p;   p += TT * 4;
    int*   p2v = (int*)p;   p += TT * 4;
    int*   etok = (int*)p;  p += EE * LIST_STRIDE * 4;
    uintptr_t q = (((uintptr_t)p) + 255) & ~(uintptr_t)255;
    __bf16* xb  = (__bf16*)q;  q += (size_t)TT * DD * 2;             // 16 MB
    __bf16* w1T = (__bf16*)q;  q += (size_t)EE * FF * DD * 2;        // 64 MB
    __bf16* w2T = (__bf16*)q;  q += (size_t)EE * DD * FF * 2;        // 64 MB
    __bf16* H   = (__bf16*)q;  q += (size_t)EE * LIST_STRIDE * FF * 2; // 256 MB
    __bf16* O   = (__bf16*)q;                                        // 64 MB

    hipMemsetAsync(sums, 0, 128, stream);

    moe_prep_kernel<<<GATE_BLOCKS + T1_BLOCKS + T2_BLOCKS, 256, 0, stream>>>(
        x, gw, e1v, e2v, g1v, g2v, sums, xb, w1, w1T, w2, w2T);
    moe_scan_kernel<<<16, 256, 0, stream>>>(e1v, e2v, g1v, g2v, rnd, sums,
                                            etok, p1v, p2v, cnt1, cnt2, imp1, imp2);

    moe_ffn1_mfma<<<2048, 512, 0, stream>>>(xb, w1T, b1, etok, cnt1, cnt2, H);
    moe_ffn2_mfma<<<512, 512, 0, stream>>>(H, w2T, b2, cnt1, cnt2, O);
    moe_combine_kernel<<<TT, 256, 0, stream>>>(O, g1v, g2v, p1v, p2v, out,
                                               sums, imp1, imp2);
}